// Round 1
// 9033.617 us; speedup vs baseline: 1.4675x; 1.4675x over previous
//
#include <hip/hip_runtime.h>

#define CCH 128
#define RT  32          // rows per block-iteration (all row counts divide 32)
#define WPAD 132        // Wt leading dim: 16B-aligned rows, breaks transpose-store conflicts

typedef float4 f4;

#define FMA4(A, W, S) \
    A.x = fmaf(W.x, S, A.x); \
    A.y = fmaf(W.y, S, A.y); \
    A.z = fmaf(W.z, S, A.z); \
    A.w = fmaf(W.w, S, A.w)

// Fused "rows x (128x128 linear) [x relu x (128x128 linear)]" kernel.
//   v[row] = sum over NSRC of src_s[idx_s ? idx_s[row] : row]
//   h      = relu(W1 v + b1)
//   y      = HASW2 ? (W2 h) : h (+eb1+eb2 if EB)
//   OUT_MODE 0: out[row] = y
//   OUT_MODE 1: atomicAdd(out[idxO[row]], y)   (segment-sum; bias of W2 must be folded elsewhere)
//   OUT_MODE 2: out[row] = y + b2 + res[row]
// W is [out,in] row-major (torch Linear).
template <int NSRC, bool HASW2, int OUT_MODE, bool EB>
__global__ __launch_bounds__(256, 1) void fused(
    const float* __restrict__ s0, const int* __restrict__ i0,
    const float* __restrict__ s1, const int* __restrict__ i1,
    const float* __restrict__ s2, const int* __restrict__ i2,
    const float* __restrict__ s3, const int* __restrict__ i3,
    const float* __restrict__ W1, const float* __restrict__ b1,
    const float* __restrict__ W2, const float* __restrict__ b2,
    const float* __restrict__ eb1, const float* __restrict__ eb2,
    float* __restrict__ out, const int* __restrict__ idxO,
    const float* __restrict__ res, int nrows)
{
    __shared__ float Wt1[CCH][WPAD];
    __shared__ float Wt2[HASW2 ? CCH : 1][WPAD];
    __shared__ float buf[CCH][RT];   // k-major staged rows; reused as hT between phases

    const int t = threadIdx.x;

    // Transposed W load (coalesced global read, padded store)
    for (int i = t; i < CCH * CCH; i += 256) {
        int c = i >> 7, k = i & 127;
        Wt1[k][c] = W1[i];
        if constexpr (HASW2) Wt2[k][c] = W2[i];
    }

    const int lane = t & 63;
    const int wave = t >> 6;
    const int c0   = (lane & 31) << 2;            // 4 channels per lane
    const int row0 = wave * 8 + (lane >> 5) * 4;  // 4 rows per lane (within tile)

    const int srow = t & 31;                      // staging: one row per thread...
    const int k0   = (t >> 5) << 4;               // ...16 k's per thread (conflict-free LDS writes)

    const f4 b1v = *(const f4*)(b1 + c0);
    f4 b2v = make_float4(0.f, 0.f, 0.f, 0.f);
    if constexpr (OUT_MODE == 2) b2v = *(const f4*)(b2 + c0);
    f4 ebv = make_float4(0.f, 0.f, 0.f, 0.f);
    if constexpr (EB) {
        const f4 e1 = *(const f4*)(eb1 + c0);
        const f4 e2 = *(const f4*)(eb2 + c0);
        ebv = make_float4(e1.x + e2.x, e1.y + e2.y, e1.z + e2.z, e1.w + e2.w);
    }

    const int niter = (nrows + RT - 1) / RT;

    f4 pf[NSRC][4];   // prefetched tile rows (issued during previous tile's compute)

    auto stage_issue = [&](int it2) {
        int row = it2 * RT + srow;
        if (row >= nrows) row = nrows - 1;   // clamp; outputs for OOB rows are guarded
        {
            int r = i0 ? i0[row] : row;
            const f4* p = (const f4*)(s0 + (size_t)r * CCH + k0);
            pf[0][0] = p[0]; pf[0][1] = p[1]; pf[0][2] = p[2]; pf[0][3] = p[3];
        }
        if constexpr (NSRC > 1) {
            int r = i1 ? i1[row] : row;
            const f4* p = (const f4*)(s1 + (size_t)r * CCH + k0);
            pf[1][0] = p[0]; pf[1][1] = p[1]; pf[1][2] = p[2]; pf[1][3] = p[3];
        }
        if constexpr (NSRC > 2) {
            int r = i2 ? i2[row] : row;
            const f4* p = (const f4*)(s2 + (size_t)r * CCH + k0);
            pf[2][0] = p[0]; pf[2][1] = p[1]; pf[2][2] = p[2]; pf[2][3] = p[3];
        }
        if constexpr (NSRC > 3) {
            int r = i3 ? i3[row] : row;
            const f4* p = (const f4*)(s3 + (size_t)r * CCH + k0);
            pf[3][0] = p[0]; pf[3][1] = p[1]; pf[3][2] = p[2]; pf[3][3] = p[3];
        }
    };

    auto gemm = [&](const float (*WT)[WPAD], f4 a[4]) {
        #pragma unroll 8
        for (int k = 0; k < CCH; ++k) {
            const f4 w = *(const f4*)&WT[k][c0];
            const f4 v = *(const f4*)&buf[k][row0];
            FMA4(a[0], w, v.x);
            FMA4(a[1], w, v.y);
            FMA4(a[2], w, v.z);
            FMA4(a[3], w, v.w);
        }
    };

    const int it0 = blockIdx.x;
    if (it0 < niter) stage_issue(it0);

    for (int it = it0; it < niter; it += gridDim.x) {
        __syncthreads();   // buf free (prev iter's reads done); waits prefetch too
        #pragma unroll
        for (int j = 0; j < 4; ++j) {
            f4 v = pf[0][j];
            if constexpr (NSRC > 1) { v.x += pf[1][j].x; v.y += pf[1][j].y; v.z += pf[1][j].z; v.w += pf[1][j].w; }
            if constexpr (NSRC > 2) { v.x += pf[2][j].x; v.y += pf[2][j].y; v.z += pf[2][j].z; v.w += pf[2][j].w; }
            if constexpr (NSRC > 3) { v.x += pf[3][j].x; v.y += pf[3][j].y; v.z += pf[3][j].z; v.w += pf[3][j].w; }
            const int kk = k0 + (j << 2);
            buf[kk + 0][srow] = v.x;
            buf[kk + 1][srow] = v.y;
            buf[kk + 2][srow] = v.z;
            buf[kk + 3][srow] = v.w;
        }
        __syncthreads();

        // prefetch next tile while this tile computes
        const int itn = it + gridDim.x;
        if (itn < niter) stage_issue(itn);

        f4 acc1[4];
        acc1[0] = acc1[1] = acc1[2] = acc1[3] = make_float4(0.f, 0.f, 0.f, 0.f);
        gemm(Wt1, acc1);

        f4 accF[4];
        if constexpr (HASW2) {
            #pragma unroll
            for (int r = 0; r < 4; ++r) {
                acc1[r].x = fmaxf(acc1[r].x + b1v.x, 0.f);
                acc1[r].y = fmaxf(acc1[r].y + b1v.y, 0.f);
                acc1[r].z = fmaxf(acc1[r].z + b1v.z, 0.f);
                acc1[r].w = fmaxf(acc1[r].w + b1v.w, 0.f);
            }
            __syncthreads();   // everyone done reading v from buf
            // transpose h into buf (k-major), 4x b128, bandwidth-optimal pattern
            *(f4*)&buf[c0 + 0][row0] = make_float4(acc1[0].x, acc1[1].x, acc1[2].x, acc1[3].x);
            *(f4*)&buf[c0 + 1][row0] = make_float4(acc1[0].y, acc1[1].y, acc1[2].y, acc1[3].y);
            *(f4*)&buf[c0 + 2][row0] = make_float4(acc1[0].z, acc1[1].z, acc1[2].z, acc1[3].z);
            *(f4*)&buf[c0 + 3][row0] = make_float4(acc1[0].w, acc1[1].w, acc1[2].w, acc1[3].w);
            __syncthreads();
            accF[0] = accF[1] = accF[2] = accF[3] = make_float4(0.f, 0.f, 0.f, 0.f);
            gemm(Wt2, accF);   // y = W2 h   (bias handled by caller/epilogue)
        } else {
            #pragma unroll
            for (int r = 0; r < 4; ++r) {
                accF[r].x = fmaxf(acc1[r].x + b1v.x, 0.f);
                accF[r].y = fmaxf(acc1[r].y + b1v.y, 0.f);
                accF[r].z = fmaxf(acc1[r].z + b1v.z, 0.f);
                accF[r].w = fmaxf(acc1[r].w + b1v.w, 0.f);
                if constexpr (EB) {
                    accF[r].x += ebv.x; accF[r].y += ebv.y;
                    accF[r].z += ebv.z; accF[r].w += ebv.w;
                }
            }
        }

        #pragma unroll
        for (int r = 0; r < 4; ++r) {
            const int row = it * RT + row0 + r;
            if (row >= nrows) continue;
            f4 y = accF[r];
            if constexpr (OUT_MODE == 0) {
                *(f4*)(out + (size_t)row * CCH + c0) = y;
            } else if constexpr (OUT_MODE == 2) {
                const f4 rv = *(const f4*)(res + (size_t)row * CCH + c0);
                y.x += b2v.x + rv.x; y.y += b2v.y + rv.y;
                y.z += b2v.z + rv.z; y.w += b2v.w + rv.w;
                *(f4*)(out + (size_t)row * CCH + c0) = y;
            } else {
                float* p = out + (size_t)idxO[row] * CCH + c0;
                unsafeAtomicAdd(p + 0, y.x);
                unsafeAtomicAdd(p + 1, y.y);
                unsafeAtomicAdd(p + 2, y.z);
                unsafeAtomicAdd(p + 3, y.w);
            }
        }
    }
}

extern "C" void kernel_launch(void* const* d_in, const int* in_sizes, int n_in,
                              void* d_out, int out_size, void* d_ws, size_t ws_size,
                              hipStream_t stream)
{
    const float* x0     = (const float*)d_in[0];
    const float* x1     = (const float*)d_in[1];
    const float* x2     = (const float*)d_in[2];
    const int*   ei1    = (const int*)d_in[3];
    const int*   ei2    = (const int*)d_in[4];
    const int*   tri111 = (const int*)d_in[5];
    const int*   tri222 = (const int*)d_in[6];
    const int*   tri112 = (const int*)d_in[7];
    const int*   inv1   = (const int*)d_in[8];
    const float* inner_W = (const float*)d_in[10];
    const float* inner_b = (const float*)d_in[11];
    const float* l111_W  = (const float*)d_in[12];
    const float* l111_b  = (const float*)d_in[13];
    const float* l222_W  = (const float*)d_in[14];
    const float* l222_b  = (const float*)d_in[15];
    const float* l211_W  = (const float*)d_in[16];
    const float* l211_b  = (const float*)d_in[17];
    const float* m0a_W   = (const float*)d_in[18];
    const float* m0a_b   = (const float*)d_in[19];
    const float* m0b_W   = (const float*)d_in[20];
    const float* m0b_b   = (const float*)d_in[21];
    const float* m1a_W   = (const float*)d_in[22];
    const float* m1a_b   = (const float*)d_in[23];
    const float* m1b_W   = (const float*)d_in[24];
    const float* m1b_b   = (const float*)d_in[25];
    const float* m2a_W   = (const float*)d_in[26];
    const float* m2a_b   = (const float*)d_in[27];
    const float* m2b_W   = (const float*)d_in[28];
    const float* m2b_b   = (const float*)d_in[29];

    const int N0 = in_sizes[0] / CCH;
    const int E1 = in_sizes[1] / CCH;
    const int E2 = in_sizes[2] / CCH;
    const int T  = in_sizes[7] / 3;

    float* o0  = (float*)d_out;               // doubles as a0 accumulator
    float* o1  = o0 + (size_t)N0 * CCH;       // doubles as a1 accumulator
    float* o2  = o1 + (size_t)E1 * CCH;       // doubles as a2 accumulator
    float* tmp = (float*)d_ws;                // l211(out_iji) segment buffer (E1 rows)

    const int G = 256;   // 1 block/CU (LDS-resident W matrices)
    const int B = 256;
    const float* np = nullptr;
    const int*   ni = nullptr;

    hipMemsetAsync(o0, 0, (size_t)N0 * CCH * sizeof(float), stream);
    hipMemsetAsync(tmp, 0, (size_t)E1 * CCH * sizeof(float), stream);

    // [A] o1 = inner(x0[s]+x0[e]) + (l111_b + l211_b)   [seg-sum biases folded once per row]
    fused<2, false, 0, true><<<G, B, 0, stream>>>(
        x0, ei1, x0, ei1 + E1, np, ni, np, ni,
        inner_W, inner_b, np, np, l111_b, l211_b, o1, ni, np, E1);

    // [B] o0 += seg(inner(x1), ei1[0])
    fused<1, false, 1, false><<<G, B, 0, stream>>>(
        x1, ni, np, ni, np, ni, np, ni,
        inner_W, inner_b, np, np, np, np, o0, ei1, np, E1);

    // [C] o2 = inner(x0[s2]+x0[e2]) + (l222_b + l211_b)
    fused<2, false, 0, true><<<G, B, 0, stream>>>(
        x0, ei2, x0, ei2 + E2, np, ni, np, ni,
        inner_W, inner_b, np, np, l222_b, l211_b, o2, ni, np, E2);

    // [D] o0 += seg(inner(x2), ei2[0])
    fused<1, false, 1, false><<<G, B, 0, stream>>>(
        x2, ni, np, ni, np, ni, np, ni,
        inner_W, inner_b, np, np, np, np, o0, ei2, np, E2);

    // [E] o1 += seg(l111 . inner(x1[t1]+x1[t2]), t0)   [linear commutes with segment-sum]
    fused<2, true, 1, false><<<G, B, 0, stream>>>(
        x1, tri111 + T, x1, tri111 + 2 * T, np, ni, np, ni,
        inner_W, inner_b, l111_W, np, np, np, o1, tri111, np, T);

    // [F] o2 += seg(l222 . inner(x2[t1]+x2[t2]), t0)
    fused<2, true, 1, false><<<G, B, 0, stream>>>(
        x2, tri222 + T, x2, tri222 + 2 * T, np, ni, np, ni,
        inner_W, inner_b, l222_W, np, np, np, o2, tri222, np, T);

    // [G] o2 += seg(l211 . inner(x1[t0]+x1[t1]), t2)
    fused<2, true, 1, false><<<G, B, 0, stream>>>(
        x1, tri112, x1, tri112 + T, np, ni, np, ni,
        inner_W, inner_b, l211_W, np, np, np, o2, tri112 + 2 * T, np, T);

    // [H] tmp = seg(l211 . inner(x1[t1]+x2[t2]), t0)   ( = l211_nobias(out_iji) )
    fused<2, true, 1, false><<<G, B, 0, stream>>>(
        x1, tri112 + T, x2, tri112 + 2 * T, np, ni, np, ni,
        inner_W, inner_b, l211_W, np, np, np, tmp, tri112, np, T);

    // [M0] o0 = m0b(relu(m0a(x0 + a0))) + x0
    fused<2, true, 2, false><<<G, B, 0, stream>>>(
        x0, ni, o0, ni, np, ni, np, ni,
        m0a_W, m0a_b, m0b_W, m0b_b, np, np, o0, ni, x0, N0);

    // [M1] o1 = m1b(relu(m1a(x1 + o1 + tmp + tmp[inv1]))) + x1
    fused<4, true, 2, false><<<G, B, 0, stream>>>(
        x1, ni, o1, ni, tmp, ni, tmp, inv1,
        m1a_W, m1a_b, m1b_W, m1b_b, np, np, o1, ni, x1, E1);

    // [M2] o2 = m2b(relu(m2a(x2 + a2))) + x2
    fused<2, true, 2, false><<<G, B, 0, stream>>>(
        x2, ni, o2, ni, np, ni, np, ni,
        m2a_W, m2a_b, m2b_W, m2b_b, np, np, o2, ni, x2, E2);
}

// Round 3
// 3977.044 us; speedup vs baseline: 3.3334x; 2.2714x over previous
//
#include <hip/hip_runtime.h>

#define CCH 128
#define RT  32          // rows per block-iteration (20000, 500000 both divide 32)

typedef float4 f4;
typedef __attribute__((ext_vector_type(8))) short bf8;     // 8 bf16 = 4 VGPR (MFMA A/B frag)
typedef __attribute__((ext_vector_type(4))) float f32x4;   // MFMA C/D frag

// --- f32 -> bf16 split helpers (RNE) ---
__device__ __forceinline__ float bfhi(float x) {
    unsigned u = __float_as_uint(x);
    return __uint_as_float((u + 0x7FFFu + ((u >> 16) & 1u)) & 0xFFFF0000u);
}
__device__ __forceinline__ unsigned pack2bf(float a, float b) {   // lo16=bf16(a), hi16=bf16(b)
    unsigned ua = __float_as_uint(a), ub = __float_as_uint(b);
    return ((ua + 0x7FFFu + ((ua >> 16) & 1u)) >> 16)
         | ((ub + 0x7FFFu + ((ub >> 16) & 1u)) & 0xFFFF0000u);
}
__device__ __forceinline__ unsigned short f2bf(float x) {
    unsigned u = __float_as_uint(x);
    return (unsigned short)((u + 0x7FFFu + ((u >> 16) & 1u)) >> 16);
}

// SPLIT2: two f32 -> packed hi-pair (exact bf16 bits) + packed lo-pair (rounded residual)
#define SPLIT2(VX, VY, HO, LO) { \
    float _hx = bfhi(VX), _hy = bfhi(VY); \
    HO = (int)((__float_as_uint(_hx) >> 16) | (__float_as_uint(_hy) & 0xFFFF0000u)); \
    LO = (int)pack2bf((VX) - _hx, (VY) - _hy); \
}
#define ADD4(A, B) { A.x += B.x; A.y += B.y; A.z += B.z; A.w += B.w; }

// One K-step (32 k's): 4 ds_read_b128 (A hi/lo x 2 row-tiles) + 12 MFMA; B-frags in VGPRs.
// A and B both use the standard layout k = (lane>>4)*8 + elem, so pairing is consistent;
// the v-plane XOR swizzle is inverted by kx (store rule: pos = (k&~7)^((row&7)<<3) | (k&7)).
#define GEMM_STEP(VH, VL, WF, ACC, KS) { \
    const int kx_ = ((KS) << 5) ^ g8x; \
    const bf8 a0h = *(const bf8*)&VH[aoff0 + kx_]; \
    const bf8 a0l = *(const bf8*)&VL[aoff0 + kx_]; \
    const bf8 a1h = *(const bf8*)&VH[aoff1 + kx_]; \
    const bf8 a1l = *(const bf8*)&VL[aoff1 + kx_]; \
    ACC[0][0] = __builtin_amdgcn_mfma_f32_16x16x32_bf16(a0h, WF[KS][0][0], ACC[0][0], 0, 0, 0); \
    ACC[0][0] = __builtin_amdgcn_mfma_f32_16x16x32_bf16(a0l, WF[KS][0][0], ACC[0][0], 0, 0, 0); \
    ACC[0][0] = __builtin_amdgcn_mfma_f32_16x16x32_bf16(a0h, WF[KS][0][1], ACC[0][0], 0, 0, 0); \
    ACC[0][1] = __builtin_amdgcn_mfma_f32_16x16x32_bf16(a0h, WF[KS][1][0], ACC[0][1], 0, 0, 0); \
    ACC[0][1] = __builtin_amdgcn_mfma_f32_16x16x32_bf16(a0l, WF[KS][1][0], ACC[0][1], 0, 0, 0); \
    ACC[0][1] = __builtin_amdgcn_mfma_f32_16x16x32_bf16(a0h, WF[KS][1][1], ACC[0][1], 0, 0, 0); \
    ACC[1][0] = __builtin_amdgcn_mfma_f32_16x16x32_bf16(a1h, WF[KS][0][0], ACC[1][0], 0, 0, 0); \
    ACC[1][0] = __builtin_amdgcn_mfma_f32_16x16x32_bf16(a1l, WF[KS][0][0], ACC[1][0], 0, 0, 0); \
    ACC[1][0] = __builtin_amdgcn_mfma_f32_16x16x32_bf16(a1h, WF[KS][0][1], ACC[1][0], 0, 0, 0); \
    ACC[1][1] = __builtin_amdgcn_mfma_f32_16x16x32_bf16(a1h, WF[KS][1][0], ACC[1][1], 0, 0, 0); \
    ACC[1][1] = __builtin_amdgcn_mfma_f32_16x16x32_bf16(a1l, WF[KS][1][0], ACC[1][1], 0, 0, 0); \
    ACC[1][1] = __builtin_amdgcn_mfma_f32_16x16x32_bf16(a1h, WF[KS][1][1], ACC[1][1], 0, 0, 0); \
}

// Fused "rows x (128x128 linear) [x relu x (128x128 linear)]", split-bf16 MFMA, W in VGPRs.
//   v[row] = sum over NSRC of src_s[idx_s ? idx_s[row] : row]
//   h      = relu(W1 v + b1)
//   y      = HASW2 ? (W2 h) : h (+eb1+eb2 if EB)
//   OUT_MODE 0: out[row] = y
//   OUT_MODE 1: atomicAdd(out[idxO[row]], y)   (bias of W2 folded elsewhere)
//   OUT_MODE 2: out[row] = y + b2 + res[row]
template <int NSRC, bool HASW2, int OUT_MODE, bool EB>
__global__ __launch_bounds__(256, HASW2 ? 2 : 3) void fused(
    const float* __restrict__ s0, const int* __restrict__ i0,
    const float* __restrict__ s1, const int* __restrict__ i1,
    const float* __restrict__ s2, const int* __restrict__ i2,
    const float* __restrict__ s3, const int* __restrict__ i3,
    const float* __restrict__ W1, const float* __restrict__ b1,
    const float* __restrict__ W2, const float* __restrict__ b2,
    const float* __restrict__ eb1, const float* __restrict__ eb2,
    float* __restrict__ out, const int* __restrict__ idxO,
    const float* __restrict__ res, int nrows)
{
    // LDS: activation planes only (hi/lo bf16, XOR-swizzled). 16 KB.
    __shared__ __align__(16) unsigned short lds[2 * RT * CCH];
    unsigned short* const vh = lds;
    unsigned short* const vl = lds + RT * CCH;

    const int t    = threadIdx.x;
    const int lane = t & 63;
    const int w    = t >> 6;
    const int lr   = lane & 15;
    const int g8   = (lane >> 4) << 3;       // k-group base within K-step
    const int g8x  = g8 ^ ((lr & 7) << 3);   // pre-XORed frag read offset
    const int cb   = w << 5;                 // wave's channel base (32 cols per wave)
    const int c0   = cb + lr;
    const int c1   = c0 + 16;
    const int aoff0 = lr * CCH;              // A row-tiles: rows lr, 16+lr
    const int aoff1 = (16 + lr) * CCH;
    const int qrow  = (lane >> 4) << 2;      // C-frag row base within 16x16 tile

    // --- W fragments into VGPRs (per-lane gather in MFMA B layout, split hi/lo) ---
    bf8 w1f[4][2][2];                        // [kstep][coltile][hi/lo]
    bf8 w2f[HASW2 ? 4 : 1][2][2];
    {
        #pragma unroll
        for (int ks = 0; ks < 4; ++ks)
        #pragma unroll
        for (int ct = 0; ct < 2; ++ct) {
            const float* p = W1 + (size_t)(cb + (ct << 4) + lr) * CCH + (ks << 5) + g8;
            const f4 u = *(const f4*)p, v = *(const f4*)(p + 4);
            int4 H, L;
            SPLIT2(u.x, u.y, H.x, L.x);
            SPLIT2(u.z, u.w, H.y, L.y);
            SPLIT2(v.x, v.y, H.z, L.z);
            SPLIT2(v.z, v.w, H.w, L.w);
            w1f[ks][ct][0] = __builtin_bit_cast(bf8, H);
            w1f[ks][ct][1] = __builtin_bit_cast(bf8, L);
        }
        if constexpr (HASW2) {
            #pragma unroll
            for (int ks = 0; ks < 4; ++ks)
            #pragma unroll
            for (int ct = 0; ct < 2; ++ct) {
                const float* p = W2 + (size_t)(cb + (ct << 4) + lr) * CCH + (ks << 5) + g8;
                const f4 u = *(const f4*)p, v = *(const f4*)(p + 4);
                int4 H, L;
                SPLIT2(u.x, u.y, H.x, L.x);
                SPLIT2(u.z, u.w, H.y, L.y);
                SPLIT2(v.x, v.y, H.z, L.z);
                SPLIT2(v.z, v.w, H.w, L.w);
                w2f[ks][ct][0] = __builtin_bit_cast(bf8, H);
                w2f[ks][ct][1] = __builtin_bit_cast(bf8, L);
            }
        }
    }

    float b1v[2] = { b1[c0], b1[c1] };
    float b2v[2] = { 0.f, 0.f }, ebv[2] = { 0.f, 0.f };
    if constexpr (OUT_MODE == 2) { b2v[0] = b2[c0]; b2v[1] = b2[c1]; }
    if constexpr (EB) { ebv[0] = eb1[c0] + eb2[c0]; ebv[1] = eb1[c1] + eb2[c1]; }

    // staging role: row = t&31, 16 consecutive k's per thread; swizzled store
    const int srow = t & 31;
    const int sk   = (t >> 5) << 4;
    const int sws2 = (srow & 7) << 3;
    const int sb0  = srow * CCH + ((sk) ^ sws2);
    const int sb1  = srow * CCH + ((sk + 8) ^ sws2);

    const int niter = (nrows + RT - 1) / RT;
    f4 pf[4];   // prefetched + summed 16 k's of this thread's staged row

    auto stage_issue = [&](int it2) {
        int row = it2 * RT + srow;
        if (row >= nrows) row = nrows - 1;
        {
            const int r = i0 ? i0[row] : row;
            const f4* p = (const f4*)(s0 + (size_t)r * CCH + sk);
            pf[0] = p[0]; pf[1] = p[1]; pf[2] = p[2]; pf[3] = p[3];
        }
        if constexpr (NSRC > 1) {
            const int r = i1 ? i1[row] : row;
            const f4* p = (const f4*)(s1 + (size_t)r * CCH + sk);
            f4 q0 = p[0], q1 = p[1], q2 = p[2], q3 = p[3];
            ADD4(pf[0], q0); ADD4(pf[1], q1); ADD4(pf[2], q2); ADD4(pf[3], q3);
        }
        if constexpr (NSRC > 2) {
            const int r = i2 ? i2[row] : row;
            const f4* p = (const f4*)(s2 + (size_t)r * CCH + sk);
            f4 q0 = p[0], q1 = p[1], q2 = p[2], q3 = p[3];
            ADD4(pf[0], q0); ADD4(pf[1], q1); ADD4(pf[2], q2); ADD4(pf[3], q3);
        }
        if constexpr (NSRC > 3) {
            const int r = i3 ? i3[row] : row;
            const f4* p = (const f4*)(s3 + (size_t)r * CCH + sk);
            f4 q0 = p[0], q1 = p[1], q2 = p[2], q3 = p[3];
            ADD4(pf[0], q0); ADD4(pf[1], q1); ADD4(pf[2], q2); ADD4(pf[3], q3);
        }
    };

    const int it0 = blockIdx.x;
    if (it0 < niter) stage_issue(it0);

    for (int it = it0; it < niter; it += gridDim.x) {
        const int rowbase = it * RT;

        __syncthreads();   // previous iter's reads of v-planes complete
        {
            int4 H, L;
            SPLIT2(pf[0].x, pf[0].y, H.x, L.x);
            SPLIT2(pf[0].z, pf[0].w, H.y, L.y);
            SPLIT2(pf[1].x, pf[1].y, H.z, L.z);
            SPLIT2(pf[1].z, pf[1].w, H.w, L.w);
            *(int4*)&vh[sb0] = H;
            *(int4*)&vl[sb0] = L;
            SPLIT2(pf[2].x, pf[2].y, H.x, L.x);
            SPLIT2(pf[2].z, pf[2].w, H.y, L.y);
            SPLIT2(pf[3].x, pf[3].y, H.z, L.z);
            SPLIT2(pf[3].z, pf[3].w, H.w, L.w);
            *(int4*)&vh[sb1] = H;
            *(int4*)&vl[sb1] = L;
        }
        __syncthreads();

        const int itn = it + gridDim.x;
        if (itn < niter) stage_issue(itn);   // HBM latency hides under GEMM

        const f32x4 zf = { 0.f, 0.f, 0.f, 0.f };
        f32x4 acc[2][2];
        acc[0][0] = zf; acc[0][1] = zf; acc[1][0] = zf; acc[1][1] = zf;
        GEMM_STEP(vh, vl, w1f, acc, 0)
        GEMM_STEP(vh, vl, w1f, acc, 1)
        GEMM_STEP(vh, vl, w1f, acc, 2)
        GEMM_STEP(vh, vl, w1f, acc, 3)

        if constexpr (!HASW2) {
            #pragma unroll
            for (int mt = 0; mt < 2; ++mt)
            #pragma unroll
            for (int j = 0; j < 2; ++j) {
                const int col = j ? c1 : c0;
                const f32x4 a = acc[mt][j];
                #pragma unroll
                for (int q = 0; q < 4; ++q) {
                    const int grow = rowbase + (mt << 4) + qrow + q;
                    if (grow >= nrows) continue;
                    float y = fmaxf(a[q] + b1v[j], 0.f);
                    if constexpr (EB) y += ebv[j];
                    if constexpr (OUT_MODE == 0) {
                        out[(size_t)grow * CCH + col] = y;
                    } else if constexpr (OUT_MODE == 2) {
                        out[(size_t)grow * CCH + col] = y + b2v[j] + res[(size_t)grow * CCH + col];
                    } else {
                        unsafeAtomicAdd(out + (size_t)idxO[grow] * CCH + col, y);
                    }
                }
            }
        } else {
            __syncthreads();   // all waves done reading v-planes
            // h = relu(acc + b1): split-bf16, swizzled scatter back into v-planes (k-dim = channel)
            #pragma unroll
            for (int mt = 0; mt < 2; ++mt)
            #pragma unroll
            for (int j = 0; j < 2; ++j) {
                const int col = j ? c1 : c0;
                const f32x4 a = acc[mt][j];
                #pragma unroll
                for (int q = 0; q < 4; ++q) {
                    const float hvf = fmaxf(a[q] + b1v[j], 0.f);
                    const float hhi = bfhi(hvf);
                    const int rr  = (mt << 4) + qrow + q;
                    const int idx = rr * CCH + (col ^ ((rr & 7) << 3));
                    vh[idx] = (unsigned short)(__float_as_uint(hhi) >> 16);
                    vl[idx] = f2bf(hvf - hhi);
                }
            }
            __syncthreads();

            f32x4 acc2[2][2];
            acc2[0][0] = zf; acc2[0][1] = zf; acc2[1][0] = zf; acc2[1][1] = zf;
            GEMM_STEP(vh, vl, w2f, acc2, 0)
            GEMM_STEP(vh, vl, w2f, acc2, 1)
            GEMM_STEP(vh, vl, w2f, acc2, 2)
            GEMM_STEP(vh, vl, w2f, acc2, 3)

            #pragma unroll
            for (int mt = 0; mt < 2; ++mt)
            #pragma unroll
            for (int j = 0; j < 2; ++j) {
                const int col = j ? c1 : c0;
                const f32x4 a = acc2[mt][j];
                #pragma unroll
                for (int q = 0; q < 4; ++q) {
                    const int grow = rowbase + (mt << 4) + qrow + q;
                    if (grow >= nrows) continue;
                    const float y = a[q];
                    if constexpr (OUT_MODE == 0) {
                        out[(size_t)grow * CCH + col] = y;
                    } else if constexpr (OUT_MODE == 2) {
                        out[(size_t)grow * CCH + col] = y + b2v[j] + res[(size_t)grow * CCH + col];
                    } else {
                        unsafeAtomicAdd(out + (size_t)idxO[grow] * CCH + col, y);
                    }
                }
            }
        }
    }
}

extern "C" void kernel_launch(void* const* d_in, const int* in_sizes, int n_in,
                              void* d_out, int out_size, void* d_ws, size_t ws_size,
                              hipStream_t stream)
{
    const float* x0     = (const float*)d_in[0];
    const float* x1     = (const float*)d_in[1];
    const float* x2     = (const float*)d_in[2];
    const int*   ei1    = (const int*)d_in[3];
    const int*   ei2    = (const int*)d_in[4];
    const int*   tri111 = (const int*)d_in[5];
    const int*   tri222 = (const int*)d_in[6];
    const int*   tri112 = (const int*)d_in[7];
    const int*   inv1   = (const int*)d_in[8];
    const float* inner_W = (const float*)d_in[10];
    const float* inner_b = (const float*)d_in[11];
    const float* l111_W  = (const float*)d_in[12];
    const float* l111_b  = (const float*)d_in[13];
    const float* l222_W  = (const float*)d_in[14];
    const float* l222_b  = (const float*)d_in[15];
    const float* l211_W  = (const float*)d_in[16];
    const float* l211_b  = (const float*)d_in[17];
    const float* m0a_W   = (const float*)d_in[18];
    const float* m0a_b   = (const float*)d_in[19];
    const float* m0b_W   = (const float*)d_in[20];
    const float* m0b_b   = (const float*)d_in[21];
    const float* m1a_W   = (const float*)d_in[22];
    const float* m1a_b   = (const float*)d_in[23];
    const float* m1b_W   = (const float*)d_in[24];
    const float* m1b_b   = (const float*)d_in[25];
    const float* m2a_W   = (const float*)d_in[26];
    const float* m2a_b   = (const float*)d_in[27];
    const float* m2b_W   = (const float*)d_in[28];
    const float* m2b_b   = (const float*)d_in[29];

    const int N0 = in_sizes[0] / CCH;
    const int E1 = in_sizes[1] / CCH;
    const int E2 = in_sizes[2] / CCH;
    const int T  = in_sizes[7] / 3;

    float* o0  = (float*)d_out;               // doubles as a0 accumulator
    float* o1  = o0 + (size_t)N0 * CCH;       // doubles as a1 accumulator
    float* o2  = o1 + (size_t)E1 * CCH;       // doubles as a2 accumulator
    float* tmp = (float*)d_ws;                // l211(out_iji) segment buffer (E1 rows)

    const int G1 = 768;  // !HASW2: ~140 VGPR -> 3 blocks/CU
    const int G2 = 512;  // HASW2:  ~200 VGPR -> 2 blocks/CU
    const int B = 256;
    const float* np = nullptr;
    const int*   ni = nullptr;

    hipMemsetAsync(o0, 0, (size_t)N0 * CCH * sizeof(float), stream);
    hipMemsetAsync(tmp, 0, (size_t)E1 * CCH * sizeof(float), stream);

    // [A] o1 = inner(x0[s]+x0[e]) + (l111_b + l211_b)
    fused<2, false, 0, true><<<G1, B, 0, stream>>>(
        x0, ei1, x0, ei1 + E1, np, ni, np, ni,
        inner_W, inner_b, np, np, l111_b, l211_b, o1, ni, np, E1);

    // [B] o0 += seg(inner(x1), ei1[0])
    fused<1, false, 1, false><<<G1, B, 0, stream>>>(
        x1, ni, np, ni, np, ni, np, ni,
        inner_W, inner_b, np, np, np, np, o0, ei1, np, E1);

    // [C] o2 = inner(x0[s2]+x0[e2]) + (l222_b + l211_b)
    fused<2, false, 0, true><<<G1, B, 0, stream>>>(
        x0, ei2, x0, ei2 + E2, np, ni, np, ni,
        inner_W, inner_b, np, np, l222_b, l211_b, o2, ni, np, E2);

    // [D] o0 += seg(inner(x2), ei2[0])
    fused<1, false, 1, false><<<G1, B, 0, stream>>>(
        x2, ni, np, ni, np, ni, np, ni,
        inner_W, inner_b, np, np, np, np, o0, ei2, np, E2);

    // [E] o1 += seg(l111 . inner(x1[t1]+x1[t2]), t0)   [linear commutes with segment-sum]
    fused<2, true, 1, false><<<G2, B, 0, stream>>>(
        x1, tri111 + T, x1, tri111 + 2 * T, np, ni, np, ni,
        inner_W, inner_b, l111_W, np, np, np, o1, tri111, np, T);

    // [F] o2 += seg(l222 . inner(x2[t1]+x2[t2]), t0)
    fused<2, true, 1, false><<<G2, B, 0, stream>>>(
        x2, tri222 + T, x2, tri222 + 2 * T, np, ni, np, ni,
        inner_W, inner_b, l222_W, np, np, np, o2, tri222, np, T);

    // [G] o2 += seg(l211 . inner(x1[t0]+x1[t1]), t2)
    fused<2, true, 1, false><<<G2, B, 0, stream>>>(
        x1, tri112, x1, tri112 + T, np, ni, np, ni,
        inner_W, inner_b, l211_W, np, np, np, o2, tri112 + 2 * T, np, T);

    // [H] tmp = seg(l211 . inner(x1[t1]+x2[t2]), t0)   ( = l211_nobias(out_iji) )
    fused<2, true, 1, false><<<G2, B, 0, stream>>>(
        x1, tri112 + T, x2, tri112 + 2 * T, np, ni, np, ni,
        inner_W, inner_b, l211_W, np, np, np, tmp, tri112, np, T);

    // [M0] o0 = m0b(relu(m0a(x0 + a0))) + x0
    fused<2, true, 2, false><<<G2, B, 0, stream>>>(
        x0, ni, o0, ni, np, ni, np, ni,
        m0a_W, m0a_b, m0b_W, m0b_b, np, np, o0, ni, x0, N0);

    // [M1] o1 = m1b(relu(m1a(x1 + o1 + tmp + tmp[inv1]))) + x1
    fused<4, true, 2, false><<<G2, B, 0, stream>>>(
        x1, ni, o1, ni, tmp, ni, tmp, inv1,
        m1a_W, m1a_b, m1b_W, m1b_b, np, np, o1, ni, x1, E1);

    // [M2] o2 = m2b(relu(m2a(x2 + a2))) + x2
    fused<2, true, 2, false><<<G2, B, 0, stream>>>(
        x2, ni, o2, ni, np, ni, np, ni,
        m2a_W, m2a_b, m2b_W, m2b_b, np, np, o2, ni, x2, E2);
}